// Round 6
// baseline (302.027 us; speedup 1.0000x reference)
//
#include <hip/hip_runtime.h>
#include <stdint.h>
#include <math.h>

#define EMB 2048
#define NHq 16
#define NGk 4
#define HD 128
#define Bb 2
#define Tt 2048
#define MROWS (Bb*Tt)      // 4096
#define QKVN 3072          // 2048 q + 512 k + 512 v
#define NQT 32             // q-tiles of 64 rows per (b,h)

typedef __bf16 bf16x8 __attribute__((ext_vector_type(8)));
typedef float f32x4 __attribute__((ext_vector_type(4)));
typedef unsigned short u16;
typedef unsigned int u32;

__device__ __forceinline__ u16 f2bf(float f) {
    unsigned int u = __float_as_uint(f);
    u += 0x7fff + ((u >> 16) & 1);          // round-to-nearest-even
    return (u16)(u >> 16);
}

__device__ __forceinline__ u32 cvt_pk_bf16(float lo, float hi) {
    u32 r;
    asm("v_cvt_pk_bf16_f32 %0, %1, %2" : "=v"(r) : "v"(lo), "v"(hi));
    return r;
}

#define GLOAD_LDS16(g, l) \
    __builtin_amdgcn_global_load_lds((const __attribute__((address_space(1))) void*)(g), \
                                     (__attribute__((address_space(3))) void*)(l), 16, 0, 0)

// ---------------- cast f32 -> bf16, vectorized ----------------
__global__ void cast_bf16_kernel(const float* __restrict__ src, u16* __restrict__ dst, int n4) {
    int i = blockIdx.x * blockDim.x + threadIdx.x;
    if (i < n4) {
        float4 v = reinterpret_cast<const float4*>(src)[i];
        ushort4 o;
        o.x = f2bf(v.x); o.y = f2bf(v.y); o.z = f2bf(v.z); o.w = f2bf(v.w);
        reinterpret_cast<ushort4*>(dst)[i] = o;
    }
}

// ---------------- RoPE cos/sin tables: [T][64] ----------------
__global__ void rope_tables_kernel(float* __restrict__ ctab, float* __restrict__ stab) {
    int t = blockIdx.x, i = threadIdx.x;     // grid T, block 64
    float inv = powf(10000.f, -2.f * (float)i / (float)HD);
    float ang = (float)t * inv;
    ctab[t * 64 + i] = cosf(ang);
    stab[t * 64 + i] = sinf(ang);
}

// ---------------- RoPE + relayout: lin[M][3072] f32 -> out[B][nh][T][HD] bf16 ----------------
__global__ void rope_kernel(const float* __restrict__ lin, const float* __restrict__ ctab,
                            const float* __restrict__ stab, u16* __restrict__ out,
                            int coloff, int nh, float scale) {
    // grid (T/4, nh, B), block (64,4)
    int i = threadIdx.x;                       // pair index 0..63
    int tt = blockIdx.x * 4 + threadIdx.y;
    int h = blockIdx.y, b = blockIdx.z;
    const float2 xv = *reinterpret_cast<const float2*>(
        &lin[((size_t)(b * Tt + tt)) * QKVN + coloff + h * HD + 2 * i]);
    float c = ctab[tt * 64 + i], s = stab[tt * 64 + i];
    ushort2 o;
    o.x = f2bf((xv.x * c - xv.y * s) * scale);
    o.y = f2bf((xv.x * s + xv.y * c) * scale);
    *reinterpret_cast<ushort2*>(&out[(((size_t)(b * nh + h)) * Tt + tt) * HD + 2 * i]) = o;
}

// ---------------- V relayout+transpose: lin -> Vt[B][NG][HD][T] bf16, kk-PERMUTED ----------------
// Within each 32-kv tile, kv index c is stored at position sigma(c) = (c&15)*2 + (c>>4),
// matching the packed P-store (cvt_pk puts cols lr and 16+lr at positions 2lr, 2lr+1).
__global__ void vtrans_kernel(const float* __restrict__ lin, u16* __restrict__ vt) {
    // grid (T/64, NG, B), block (64,8)
    int tx = threadIdx.x, dy = threadIdx.y;
    int tt = blockIdx.x * 64 + tx;
    int g = blockIdx.y, b = blockIdx.z;
    int ttp = (tt & ~31) | (((tt & 15) << 1) | ((tt >> 4) & 1));   // permuted position
    const float* src = &lin[((size_t)(b * Tt + tt)) * QKVN + EMB + NGk * HD + g * HD];
    u16* dst = &vt[(((size_t)(b * NGk + g)) * HD) * Tt + ttp];
    #pragma unroll
    for (int k = 0; k < 16; ++k) {
        int d = dy + k * 8;
        dst[(size_t)d * Tt] = f2bf(src[d]);
    }
}

// ---------------- bf16 GEMM: C[M][N] f32 = A[M][K]bf16 @ W[N][K]bf16 ^T ----------------
__global__ __launch_bounds__(256) void gemm_bt(const u16* __restrict__ A, const u16* __restrict__ W,
                                               float* __restrict__ C, int M, int N, int K) {
    __shared__ u16 Atile[128 * 32];
    __shared__ u16 Btile[128 * 32];
    const int brow = blockIdx.x * 128;
    const int bcol = blockIdx.y * 128;
    const int t = threadIdx.x;
    const int w = t >> 6, l = t & 63;
    const int lr = l & 15, lq = l >> 4;
    const int wr = (w >> 1) * 64, wc = (w & 1) * 64;
    f32x4 acc[4][4] = {};
    const int nkt = K >> 5;
    for (int kt = 0; kt < nkt; ++kt) {
        const int k0 = kt * 32;
        #pragma unroll
        for (int i = 0; i < 2; ++i) {
            int f = i * 256 + t;
            int row = f >> 2, cb = (f & 3) * 8;
            GLOAD_LDS16(A + (size_t)(brow + row) * K + k0 + cb, &Atile[(i * 256 + w * 64) * 8]);
            GLOAD_LDS16(W + (size_t)(bcol + row) * K + k0 + cb, &Btile[(i * 256 + w * 64) * 8]);
        }
        __syncthreads();
        bf16x8 a[4], b[4];
        #pragma unroll
        for (int m = 0; m < 4; ++m)
            a[m] = *reinterpret_cast<const bf16x8*>(&Atile[(wr + m * 16 + lr) * 32 + lq * 8]);
        #pragma unroll
        for (int n = 0; n < 4; ++n)
            b[n] = *reinterpret_cast<const bf16x8*>(&Btile[(wc + n * 16 + lr) * 32 + lq * 8]);
        #pragma unroll
        for (int m = 0; m < 4; ++m)
            #pragma unroll
            for (int n = 0; n < 4; ++n)
                acc[m][n] = __builtin_amdgcn_mfma_f32_16x16x32_bf16(a[m], b[n], acc[m][n], 0, 0, 0);
        __syncthreads();
    }
    #pragma unroll
    for (int m = 0; m < 4; ++m)
        #pragma unroll
        for (int n = 0; n < 4; ++n)
            #pragma unroll
            for (int r = 0; r < 4; ++r)
                C[(size_t)(brow + wr + m * 16 + lq * 4 + r) * N + bcol + wc + n * 16 + lr] = acc[m][n][r];
}

// ---------------- flash attention v6: parity-split kv, KVBLK=32, f32 partials ----------------
// Fixed-shift softmax (no running max) makes kv-partials trivially combinable:
// O = sum O_par, l = sum l_par. Block (ilo,par,h,b): diagonal pair {ilo, 31-ilo},
// kv tiles kt = par, par+2, ... -> per-wave work constant. 36 KB LDS -> 4 blocks/CU by LDS.
// Writes raw f32 partials: Opart[pblk][128rows][128d] (+hi rows 0-63, lo rows 64-127), Lpart[pblk][128].
__global__ __launch_bounds__(256) void flash_attn(const u16* __restrict__ Q, const u16* __restrict__ K,
                                                  const u16* __restrict__ Vt,
                                                  float* __restrict__ Opart, float* __restrict__ Lpart) {
    __shared__ u16 Klds[2][32 * 128];     // [kv 32][d 128], row-swizzled
    __shared__ u16 Vlds[2][128 * 32];     // [d 128][kv' 32], linear (64B rows conflict-free)
    __shared__ u16 Plds[4][16 * 32];      // per-wave [qrow 16][kv' 32]
    const int ilo = blockIdx.x >> 1;      // 0..15
    const int par = blockIdx.x & 1;       // kv-tile parity
    const int ihi = NQT - 1 - ilo;        // 16..31
    const int h = blockIdx.y;
    const int b = blockIdx.z;
    const int g = h >> 2;
    const int t = threadIdx.x;
    const int w = t >> 6, l = t & 63;
    const int lr = l & 15, lq = l >> 4;

    const size_t qhead = ((size_t)(b * NHq + h)) * Tt;
    const size_t qblo = (qhead + ilo * 64 + w * 16) * HD;
    const size_t qbhi = (qhead + ihi * 64 + w * 16) * HD;
    bf16x8 qfl[4], qfh[4];
    #pragma unroll
    for (int d = 0; d < 4; ++d) {
        qfl[d] = *reinterpret_cast<const bf16x8*>(&Q[qblo + (size_t)lr * HD + d * 32 + lq * 8]);
        qfh[d] = *reinterpret_cast<const bf16x8*>(&Q[qbhi + (size_t)lr * HD + d * 32 + lq * 8]);
    }
    bf16x8 ones;
    #pragma unroll
    for (int j = 0; j < 8; ++j) ones[j] = (__bf16)1.0f;

    f32x4 ol[8] = {}, oh[8] = {};
    f32x4 lsum_l = {}, lsum_h = {};

    const int qlo0 = ilo * 64 + w * 16 + lq * 4;
    const int qhi0 = ihi * 64 + w * 16 + lq * 4;
    const size_t kbase  = ((size_t)(b * NGk + g)) * Tt * HD;
    const size_t vtbase = ((size_t)(b * NGk + g)) * HD * Tt;
    const int nsteps = NQT - ilo;         // tiles this par-block processes

    // per-lane staging offsets (K source pre-swizzled for linear gload_lds dest; V linear)
    int kofs[2], vofs[2];
    #pragma unroll
    for (int j = 0; j < 2; ++j) {
        int c = j * 256 + w * 64 + l;
        int krow = c >> 4;                              // 0..31
        kofs[j] = krow * HD + ((l & 15) ^ (krow & 7)) * 8;
        int vd = c >> 2;                                // 0..127
        vofs[j] = vd * Tt + (l & 3) * 8;
    }

    // prologue: stage tile kt=par into buf 0
    {
        const size_t kp = (size_t)par * 32;
        #pragma unroll
        for (int j = 0; j < 2; ++j) {
            GLOAD_LDS16(K + kbase + kp * HD + kofs[j], &Klds[0][j * 2048 + w * 512]);
            GLOAD_LDS16(Vt + vtbase + kp + vofs[j], &Vlds[0][j * 2048 + w * 512]);
        }
    }
    int cur = 0;

    for (int i = 0; i < nsteps; ++i) {
        const int kt = par + 2 * i;
        const int kp0 = kt * 32;
        __syncthreads();                      // tile resident in buf[cur] (drains vmcnt)
        if (i + 1 < nsteps) {                 // issue tile kt+2 -> buf[cur^1]
            const size_t kp = (size_t)(kt + 2) * 32;
            #pragma unroll
            for (int j = 0; j < 2; ++j) {
                GLOAD_LDS16(K + kbase + kp * HD + kofs[j], &Klds[cur ^ 1][j * 2048 + w * 512]);
                GLOAD_LDS16(Vt + vtbase + kp + vofs[j], &Vlds[cur ^ 1][j * 2048 + w * 512]);
            }
        }
        const u16* Kb = Klds[cur];
        const u16* Vb = Vlds[cur];

        const bool lo_act = (kt <= 2 * ilo + 1);
        // ---- S = Q K^T : 2 col-tiles of 16, K-frags shared between lo/hi ----
        f32x4 sl[2] = {}, sh[2] = {};
        __builtin_amdgcn_s_setprio(1);
        #pragma unroll
        for (int ct = 0; ct < 2; ++ct) {
            #pragma unroll
            for (int d = 0; d < 4; ++d) {
                int row = ct * 16 + lr;
                int bo = row * 256 + ((d * 64 + lq * 16) ^ ((row & 7) << 4));
                bf16x8 kf = *reinterpret_cast<const bf16x8*>((const char*)Kb + bo);
                if (lo_act) sl[ct] = __builtin_amdgcn_mfma_f32_16x16x32_bf16(qfl[d], kf, sl[ct], 0, 0, 0);
                sh[ct] = __builtin_amdgcn_mfma_f32_16x16x32_bf16(qfh[d], kf, sh[ct], 0, 0, 0);
            }
        }
        __builtin_amdgcn_s_setprio(0);

        // ---- fixed-shift softmax, packed P-store (cols lr,16+lr -> positions 2lr,2lr+1) ----
        {   // hi half (always active)
            const bool diag = (kt >= 2 * ihi);
            float e[2][4];
            #pragma unroll
            for (int ct = 0; ct < 2; ++ct)
                #pragma unroll
                for (int r = 0; r < 4; ++r) {
                    float v = sh[ct][r];
                    if (diag && (kp0 + ct * 16 + lr > qhi0 + r)) v = -1e30f;
                    e[ct][r] = exp2f(v);
                }
            #pragma unroll
            for (int r = 0; r < 4; ++r) {
                int row = lq * 4 + r;
                *reinterpret_cast<u32*>((char*)Plds[w] + row * 64 + lr * 4) = cvt_pk_bf16(e[0][r], e[1][r]);
            }
        }
        bf16x8 pfh = *reinterpret_cast<const bf16x8*>((const char*)Plds[w] + lr * 64 + lq * 16);
        bf16x8 pfl;
        if (lo_act) {
            const bool diag = (kt >= 2 * ilo);
            float e[2][4];
            #pragma unroll
            for (int ct = 0; ct < 2; ++ct)
                #pragma unroll
                for (int r = 0; r < 4; ++r) {
                    float v = sl[ct][r];
                    if (diag && (kp0 + ct * 16 + lr > qlo0 + r)) v = -1e30f;
                    e[ct][r] = exp2f(v);
                }
            #pragma unroll
            for (int r = 0; r < 4; ++r) {
                int row = lq * 4 + r;
                *reinterpret_cast<u32*>((char*)Plds[w] + row * 64 + lr * 4) = cvt_pk_bf16(e[0][r], e[1][r]);
            }
            pfl = *reinterpret_cast<const bf16x8*>((const char*)Plds[w] + lr * 64 + lq * 16);
        }

        // ---- O += P V ; l += P . ones (V-frags shared lo/hi; kv' space matches P) ----
        __builtin_amdgcn_s_setprio(1);
        #pragma unroll
        for (int n = 0; n < 8; ++n) {
            int bv = (n * 16 + lr) * 64 + lq * 16;
            bf16x8 vf = *reinterpret_cast<const bf16x8*>((const char*)Vb + bv);
            oh[n] = __builtin_amdgcn_mfma_f32_16x16x32_bf16(pfh, vf, oh[n], 0, 0, 0);
            if (lo_act) ol[n] = __builtin_amdgcn_mfma_f32_16x16x32_bf16(pfl, vf, ol[n], 0, 0, 0);
        }
        lsum_h = __builtin_amdgcn_mfma_f32_16x16x32_bf16(pfh, ones, lsum_h, 0, 0, 0);
        if (lo_act) lsum_l = __builtin_amdgcn_mfma_f32_16x16x32_bf16(pfl, ones, lsum_l, 0, 0, 0);
        __builtin_amdgcn_s_setprio(0);
        cur ^= 1;
    }

    // ---- epilogue: write raw f32 partials (hi rows 0-63, lo rows 64-127) ----
    const int pblk = (((b * NHq + h) * 16) + ilo) * 2 + par;
    float* Po = Opart + (size_t)pblk * 16384;
    #pragma unroll
    for (int n = 0; n < 8; ++n)
        #pragma unroll
        for (int r = 0; r < 4; ++r) {
            int row = w * 16 + lq * 4 + r, col = n * 16 + lr;
            Po[row * 128 + col] = oh[n][r];
            Po[(64 + row) * 128 + col] = ol[n][r];
        }
    if (lr == 0) {
        float* Lp = Lpart + (size_t)pblk * 128;
        #pragma unroll
        for (int r = 0; r < 4; ++r) {
            int row = w * 16 + lq * 4 + r;
            Lp[row] = lsum_h[r];
            Lp[64 + row] = lsum_l[r];
        }
    }
}

// ---------------- combine parity partials -> attnout bf16 [B][T][EMB] ----------------
__global__ __launch_bounds__(256) void reduce_attn(const float* __restrict__ Opart,
                                                   const float* __restrict__ Lpart,
                                                   u16* __restrict__ Out) {
    const int qb = blockIdx.x;            // output q-tile 0..31
    const int h = blockIdx.y, b = blockIdx.z;
    const bool ishi = (qb >= 16);
    const int ilo = ishi ? (NQT - 1 - qb) : qb;
    const int rowoff = ishi ? 0 : 64;
    const size_t pb = (((size_t)(b * NHq + h) * 16) + ilo) * 2;
    const float* O0 = Opart + pb * 16384;
    const float* O1 = O0 + 16384;
    const float* L0 = Lpart + pb * 128;
    const float* L1 = L0 + 128;
    const int tid = threadIdx.x;
    const int r = tid >> 2;               // row 0..63
    const int qtr = tid & 3;              // 32-col quarter
    const float inv = 1.f / (L0[rowoff + r] + L1[rowoff + r]);
    const float* s0 = O0 + (rowoff + r) * 128 + qtr * 32;
    const float* s1 = O1 + (rowoff + r) * 128 + qtr * 32;
    u16* dst = Out + ((size_t)(b * Tt) + qb * 64 + r) * EMB + h * HD + qtr * 32;
    #pragma unroll
    for (int v = 0; v < 8; ++v) {
        float4 a = reinterpret_cast<const float4*>(s0)[v];
        float4 c = reinterpret_cast<const float4*>(s1)[v];
        ushort4 o;
        o.x = f2bf((a.x + c.x) * inv);
        o.y = f2bf((a.y + c.y) * inv);
        o.z = f2bf((a.z + c.z) * inv);
        o.w = f2bf((a.w + c.w) * inv);
        reinterpret_cast<ushort4*>(dst)[v] = o;
    }
}

// ---------------- launcher ----------------
extern "C" void kernel_launch(void* const* d_in, const int* in_sizes, int n_in,
                              void* d_out, int out_size, void* d_ws, size_t ws_size,
                              hipStream_t stream) {
    (void)in_sizes; (void)n_in; (void)out_size; (void)ws_size;
    const float* x  = (const float*)d_in[0];
    const float* Wq = (const float*)d_in[1];
    const float* Wk = (const float*)d_in[2];
    const float* Wv = (const float*)d_in[3];
    const float* Wo = (const float*)d_in[4];
    float* out = (float*)d_out;

    char* ws = (char*)d_ws;
    size_t off = 0;
    auto alloc = [&](size_t bytes) { char* p = ws + off; off += (bytes + 255) & ~(size_t)255; return p; };

    u16* w_bf    = (u16*)alloc((size_t)(QKVN * EMB + EMB * EMB) * 2);  // Wq|Wk|Wv then Wo
    u16* x_bf    = (u16*)alloc((size_t)MROWS * EMB * 2);               // also: partials start
    float* qkv_lin = (float*)alloc((size_t)MROWS * QKVN * 4);          // partials continue
    u16* Qb      = (u16*)alloc((size_t)Bb * NHq * Tt * HD * 2);        // also: attnout after flash
    u16* Kb      = (u16*)alloc((size_t)Bb * NGk * Tt * HD * 2);
    u16* Vtb     = (u16*)alloc((size_t)Bb * NGk * HD * Tt * 2);
    float* ctab  = (float*)alloc((size_t)Tt * 64 * 4);
    float* stab  = (float*)alloc((size_t)Tt * 64 * 4);
    float* lpart = (float*)alloc((size_t)1024 * 128 * 4);

    // partials: 1024 blocks x 128x128 f32 = 64 MB exactly over x_bf+qkv_lin (dead by flash time)
    float* opart = (float*)x_bf;
    u16* attnout = Qb;              // Qb dead after flash

    u16* wq_bf = w_bf;
    u16* wk_bf = w_bf + (size_t)EMB * EMB;
    u16* wv_bf = wk_bf + (size_t)NGk * HD * EMB;
    u16* wo_bf = wv_bf + (size_t)NGk * HD * EMB;

    // 1. casts
    cast_bf16_kernel<<<(MROWS * EMB / 4 + 255) / 256, 256, 0, stream>>>(x, x_bf, MROWS * EMB / 4);
    cast_bf16_kernel<<<(EMB * EMB / 4 + 255) / 256, 256, 0, stream>>>(Wq, wq_bf, EMB * EMB / 4);
    cast_bf16_kernel<<<(NGk * HD * EMB / 4 + 255) / 256, 256, 0, stream>>>(Wk, wk_bf, NGk * HD * EMB / 4);
    cast_bf16_kernel<<<(NGk * HD * EMB / 4 + 255) / 256, 256, 0, stream>>>(Wv, wv_bf, NGk * HD * EMB / 4);
    cast_bf16_kernel<<<(EMB * EMB / 4 + 255) / 256, 256, 0, stream>>>(Wo, wo_bf, EMB * EMB / 4);
    rope_tables_kernel<<<Tt, 64, 0, stream>>>(ctab, stab);

    // 2. fused QKV projection: qkv_lin[4096][3072] = x_bf @ [Wq;Wk;Wv]^T
    gemm_bt<<<dim3(MROWS / 128, QKVN / 128), 256, 0, stream>>>(x_bf, w_bf, qkv_lin, MROWS, QKVN, EMB);

    // 3. RoPE + relayout (+ fold softmax scale*log2e into Q)
    const float qscale = 1.44269504088896f / sqrtf((float)HD);
    rope_kernel<<<dim3(Tt / 4, NHq, Bb), dim3(64, 4), 0, stream>>>(qkv_lin, ctab, stab, Qb, 0, NHq, qscale);
    rope_kernel<<<dim3(Tt / 4, NGk, Bb), dim3(64, 4), 0, stream>>>(qkv_lin, ctab, stab, Kb, EMB, NGk, 1.0f);
    vtrans_kernel<<<dim3(Tt / 64, NGk, Bb), dim3(64, 8), 0, stream>>>(qkv_lin, Vtb);

    // 4. flash attention (parity-split kv) -> f32 partials over x_bf+qkv_lin
    flash_attn<<<dim3(NQT, NHq, Bb), 256, 0, stream>>>(Qb, Kb, Vtb, opart, lpart);

    // 4b. combine partials -> attnout bf16 (over Qb)
    reduce_attn<<<dim3(NQT, NHq, Bb), 256, 0, stream>>>(opart, lpart, attnout);

    // 5. output projection: out = attnout @ Wo^T  (f32 out)
    gemm_bt<<<dim3(MROWS / 128, EMB / 128), 256, 0, stream>>>(attnout, wo_bf, out, MROWS, EMB, EMB);
}

// Round 7
// 266.908 us; speedup vs baseline: 1.1316x; 1.1316x over previous
//
#include <hip/hip_runtime.h>
#include <stdint.h>
#include <math.h>

#define EMB 2048
#define NHq 16
#define NGk 4
#define HD 128
#define Bb 2
#define Tt 2048
#define MROWS (Bb*Tt)      // 4096
#define QKVN 3072          // 2048 q + 512 k + 512 v
#define NQT 32             // q-tiles of 64 rows per (b,h)

typedef __bf16 bf16x8 __attribute__((ext_vector_type(8)));
typedef float f32x4 __attribute__((ext_vector_type(4)));
typedef unsigned short u16;
typedef unsigned int u32;

__device__ __forceinline__ u16 f2bf(float f) {
    unsigned int u = __float_as_uint(f);
    u += 0x7fff + ((u >> 16) & 1);          // round-to-nearest-even
    return (u16)(u >> 16);
}

__device__ __forceinline__ u32 cvt_pk_bf16(float lo, float hi) {
    u32 r;
    asm("v_cvt_pk_bf16_f32 %0, %1, %2" : "=v"(r) : "v"(lo), "v"(hi));
    return r;
}

#define GLOAD_LDS16(g, l) \
    __builtin_amdgcn_global_load_lds((const __attribute__((address_space(1))) void*)(g), \
                                     (__attribute__((address_space(3))) void*)(l), 16, 0, 0)

// ---------------- cast f32 -> bf16, vectorized ----------------
__global__ void cast_bf16_kernel(const float* __restrict__ src, u16* __restrict__ dst, int n4) {
    int i = blockIdx.x * blockDim.x + threadIdx.x;
    if (i < n4) {
        float4 v = reinterpret_cast<const float4*>(src)[i];
        ushort4 o;
        o.x = f2bf(v.x); o.y = f2bf(v.y); o.z = f2bf(v.z); o.w = f2bf(v.w);
        reinterpret_cast<ushort4*>(dst)[i] = o;
    }
}

// ---------------- RoPE cos/sin tables: [T][64] ----------------
__global__ void rope_tables_kernel(float* __restrict__ ctab, float* __restrict__ stab) {
    int t = blockIdx.x, i = threadIdx.x;     // grid T, block 64
    float inv = powf(10000.f, -2.f * (float)i / (float)HD);
    float ang = (float)t * inv;
    ctab[t * 64 + i] = cosf(ang);
    stab[t * 64 + i] = sinf(ang);
}

// ---------------- RoPE + relayout: lin[M][3072] f32 -> out[B][nh][T][HD] bf16 ----------------
__global__ void rope_kernel(const float* __restrict__ lin, const float* __restrict__ ctab,
                            const float* __restrict__ stab, u16* __restrict__ out,
                            int coloff, int nh, float scale) {
    // grid (T/4, nh, B), block (64,4)
    int i = threadIdx.x;                       // pair index 0..63
    int tt = blockIdx.x * 4 + threadIdx.y;
    int h = blockIdx.y, b = blockIdx.z;
    const float2 xv = *reinterpret_cast<const float2*>(
        &lin[((size_t)(b * Tt + tt)) * QKVN + coloff + h * HD + 2 * i]);
    float c = ctab[tt * 64 + i], s = stab[tt * 64 + i];
    ushort2 o;
    o.x = f2bf((xv.x * c - xv.y * s) * scale);
    o.y = f2bf((xv.x * s + xv.y * c) * scale);
    *reinterpret_cast<ushort2*>(&out[(((size_t)(b * nh + h)) * Tt + tt) * HD + 2 * i]) = o;
}

// ---------------- V relayout+transpose: lin -> Vt[B][NG][HD][T] bf16, kk-PERMUTED ----------------
// Within each 32-kv tile, kv index c is stored at position sigma(c) = (c&15)*2 + (c>>4),
// matching the packed P-store (cvt_pk puts cols lr and 16+lr at positions 2lr, 2lr+1).
__global__ void vtrans_kernel(const float* __restrict__ lin, u16* __restrict__ vt) {
    // grid (T/64, NG, B), block (64,8)
    int tx = threadIdx.x, dy = threadIdx.y;
    int tt = blockIdx.x * 64 + tx;
    int g = blockIdx.y, b = blockIdx.z;
    int ttp = (tt & ~31) | (((tt & 15) << 1) | ((tt >> 4) & 1));   // permuted position
    const float* src = &lin[((size_t)(b * Tt + tt)) * QKVN + EMB + NGk * HD + g * HD];
    u16* dst = &vt[(((size_t)(b * NGk + g)) * HD) * Tt + ttp];
    #pragma unroll
    for (int k = 0; k < 16; ++k) {
        int d = dy + k * 8;
        dst[(size_t)d * Tt] = f2bf(src[d]);
    }
}

// ---------------- bf16 GEMM: C[M][N] f32 = A[M][K]bf16 @ W[N][K]bf16 ^T ----------------
__global__ __launch_bounds__(256) void gemm_bt(const u16* __restrict__ A, const u16* __restrict__ W,
                                               float* __restrict__ C, int M, int N, int K) {
    __shared__ u16 Atile[128 * 32];
    __shared__ u16 Btile[128 * 32];
    const int brow = blockIdx.x * 128;
    const int bcol = blockIdx.y * 128;
    const int t = threadIdx.x;
    const int w = t >> 6, l = t & 63;
    const int lr = l & 15, lq = l >> 4;
    const int wr = (w >> 1) * 64, wc = (w & 1) * 64;
    f32x4 acc[4][4] = {};
    const int nkt = K >> 5;
    for (int kt = 0; kt < nkt; ++kt) {
        const int k0 = kt * 32;
        #pragma unroll
        for (int i = 0; i < 2; ++i) {
            int f = i * 256 + t;
            int row = f >> 2, cb = (f & 3) * 8;
            GLOAD_LDS16(A + (size_t)(brow + row) * K + k0 + cb, &Atile[(i * 256 + w * 64) * 8]);
            GLOAD_LDS16(W + (size_t)(bcol + row) * K + k0 + cb, &Btile[(i * 256 + w * 64) * 8]);
        }
        __syncthreads();
        bf16x8 a[4], b[4];
        #pragma unroll
        for (int m = 0; m < 4; ++m)
            a[m] = *reinterpret_cast<const bf16x8*>(&Atile[(wr + m * 16 + lr) * 32 + lq * 8]);
        #pragma unroll
        for (int n = 0; n < 4; ++n)
            b[n] = *reinterpret_cast<const bf16x8*>(&Btile[(wc + n * 16 + lr) * 32 + lq * 8]);
        #pragma unroll
        for (int m = 0; m < 4; ++m)
            #pragma unroll
            for (int n = 0; n < 4; ++n)
                acc[m][n] = __builtin_amdgcn_mfma_f32_16x16x32_bf16(a[m], b[n], acc[m][n], 0, 0, 0);
        __syncthreads();
    }
    #pragma unroll
    for (int m = 0; m < 4; ++m)
        #pragma unroll
        for (int n = 0; n < 4; ++n)
            #pragma unroll
            for (int r = 0; r < 4; ++r)
                C[(size_t)(brow + wr + m * 16 + lq * 4 + r) * N + bcol + wc + n * 16 + lr] = acc[m][n][r];
}

// ---------------- flash attention v7: 8 waves, kv-half split, fixed-shift softmax ----------------
// Block = diagonal pair {ilo, 31-ilo} (128 q rows), 512 threads = 8 waves.
// Waves 0-3 handle kv[0..31], waves 4-7 kv[32..63] of each staged 64-kv tile; wave w&3
// owns q-rows (w&3)*16..+15 of BOTH tiles. Fixed-shift softmax (no running max) makes
// the kv-halves trivially combinable: O = O_h0 + O_h1, l = l_h0 + l_h1, exchanged once
// through LDS (aliasing dead K/V buffers) at the epilogue.
__global__ __launch_bounds__(512) void flash_attn(const u16* __restrict__ Q, const u16* __restrict__ K,
                                                  const u16* __restrict__ Vt, u16* __restrict__ Out) {
    __shared__ __align__(16) char smem[73728];   // K 2x16K | V 2x16K | P 8x1K
    u16* KldsBase = (u16*)smem;
    u16* VldsBase = (u16*)(smem + 32768);
    const int ilo = blockIdx.x;           // 0..15
    const int ihi = NQT - 1 - ilo;        // 16..31
    const int h = blockIdx.y;
    const int b = blockIdx.z;
    const int g = h >> 2;
    const int t = threadIdx.x;
    const int w = t >> 6, l = t & 63;
    const int wq = w & 3, half = w >> 2;
    const int lr = l & 15, lq = l >> 4;
    char* Pw = smem + 65536 + w * 1024;   // per-wave P tile [16 q][32 kv'] bf16, slot-swizzled

    // Q fragments: 16 rows of lo tile + 16 rows of hi tile (wave pairs w, w+4 share rows)
    const size_t qhead = ((size_t)(b * NHq + h)) * Tt;
    const size_t qblo = (qhead + ilo * 64 + wq * 16) * HD;
    const size_t qbhi = (qhead + ihi * 64 + wq * 16) * HD;
    bf16x8 qfl[4], qfh[4];
    #pragma unroll
    for (int d = 0; d < 4; ++d) {
        qfl[d] = *reinterpret_cast<const bf16x8*>(&Q[qblo + (size_t)lr * HD + d * 32 + lq * 8]);
        qfh[d] = *reinterpret_cast<const bf16x8*>(&Q[qbhi + (size_t)lr * HD + d * 32 + lq * 8]);
    }
    bf16x8 ones;
    #pragma unroll
    for (int j = 0; j < 8; ++j) ones[j] = (__bf16)1.0f;

    f32x4 ol[8] = {}, oh[8] = {};
    f32x4 lsl = {}, lsh = {};

    const int qlo0 = ilo * 64 + wq * 16 + lq * 4;
    const int qhi0 = ihi * 64 + wq * 16 + lq * 4;
    const size_t kbase  = ((size_t)(b * NGk + g)) * Tt * HD;
    const size_t vtbase = ((size_t)(b * NGk + g)) * HD * Tt;
    const int nkt = NQT - ilo;            // 17..32 staged tiles

    // staging: 512 threads x 2 chunks of 16B per operand per tile.
    // K tile [64 kv][128 d]: chunk c = j*512 + w*64 + l -> row c>>4, in-row chunk l&15,
    //   source pre-swizzled by ^(row&7) so linear LDS dest yields the swizzled read layout.
    // V tile [128 d][64 kv']: row c>>3, in-row chunk l&7, same pre-swizzle.
    int kofs[2], vofs[2];
    #pragma unroll
    for (int j = 0; j < 2; ++j) {
        int krow = j * 32 + w * 4 + (l >> 4);
        kofs[j] = krow * HD + (((l & 15) ^ (krow & 7)) * 8);
        int vrow = j * 64 + w * 8 + (l >> 3);
        vofs[j] = vrow * (int)Tt + (((l & 7) ^ (vrow & 7)) * 8);
    }

    // prologue: stage tile 0 into buf 0
    #pragma unroll
    for (int j = 0; j < 2; ++j) {
        GLOAD_LDS16(K + kbase + kofs[j], KldsBase + (j * 512 + w * 64) * 8);
        GLOAD_LDS16(Vt + vtbase + vofs[j], VldsBase + (j * 512 + w * 64) * 8);
    }
    int cur = 0;

    for (int kt = 0; kt < nkt; ++kt) {
        const int kp0 = kt * 64;
        __syncthreads();                      // tile kt resident in buf[cur] (drains vmcnt)
        if (kt + 1 < nkt) {                   // issue next tile -> buf[cur^1]
            #pragma unroll
            for (int j = 0; j < 2; ++j) {
                GLOAD_LDS16(K + kbase + (size_t)(kp0 + 64) * HD + kofs[j],
                            KldsBase + (cur ^ 1) * 8192 + (j * 512 + w * 64) * 8);
                GLOAD_LDS16(Vt + vtbase + (kp0 + 64) + vofs[j],
                            VldsBase + (cur ^ 1) * 8192 + (j * 512 + w * 64) * 8);
            }
        }
        const char* Kb = smem + cur * 16384;
        const char* Vb = smem + 32768 + cur * 16384;

        const bool lo_act = (kt <= ilo);
        // ---- S = Q K^T over this wave's kv half (2 col-tiles of 16) ----
        f32x4 sl[2] = {}, sh[2] = {};
        __builtin_amdgcn_s_setprio(1);
        #pragma unroll
        for (int ct = 0; ct < 2; ++ct) {
            #pragma unroll
            for (int d = 0; d < 4; ++d) {
                int row = half * 32 + ct * 16 + lr;
                int bo = row * 256 + ((d * 64 + lq * 16) ^ ((row & 7) << 4));
                bf16x8 kf = *reinterpret_cast<const bf16x8*>(Kb + bo);
                if (lo_act) sl[ct] = __builtin_amdgcn_mfma_f32_16x16x32_bf16(qfl[d], kf, sl[ct], 0, 0, 0);
                sh[ct] = __builtin_amdgcn_mfma_f32_16x16x32_bf16(qfh[d], kf, sh[ct], 0, 0, 0);
            }
        }
        __builtin_amdgcn_s_setprio(0);

        // ---- fixed-shift softmax, packed P-store (slot-swizzled, conflict-free read) ----
        // write: cols (lr,16+lr) -> sigma positions (2lr,2lr+1); u32 at
        //   row*64 + ((lr>>2)^(row&3))*16 + (lr&3)*4.
        // read: lane (lr,lq) b128 at lr*64 + ((lq^(lr&3))*16) -> 64 distinct 16B slots.
        {   // hi half (always active)
            const bool diag = (kt == nkt - 1);
            float e[2][4];
            #pragma unroll
            for (int ct = 0; ct < 2; ++ct)
                #pragma unroll
                for (int r = 0; r < 4; ++r) {
                    float v = sh[ct][r];
                    if (diag && (kp0 + half * 32 + ct * 16 + lr > qhi0 + r)) v = -1e30f;
                    e[ct][r] = exp2f(v);
                }
            #pragma unroll
            for (int r = 0; r < 4; ++r) {
                int row = lq * 4 + r;
                int bo = row * 64 + (((lr >> 2) ^ (row & 3)) << 4) + (lr & 3) * 4;
                *reinterpret_cast<u32*>(Pw + bo) = cvt_pk_bf16(e[0][r], e[1][r]);
            }
        }
        bf16x8 pfh = *reinterpret_cast<const bf16x8*>(Pw + lr * 64 + ((lq ^ (lr & 3)) << 4));
        bf16x8 pfl;
        if (lo_act) {
            const bool diag = (kt == ilo);
            float e[2][4];
            #pragma unroll
            for (int ct = 0; ct < 2; ++ct)
                #pragma unroll
                for (int r = 0; r < 4; ++r) {
                    float v = sl[ct][r];
                    if (diag && (kp0 + half * 32 + ct * 16 + lr > qlo0 + r)) v = -1e30f;
                    e[ct][r] = exp2f(v);
                }
            #pragma unroll
            for (int r = 0; r < 4; ++r) {
                int row = lq * 4 + r;
                int bo = row * 64 + (((lr >> 2) ^ (row & 3)) << 4) + (lr & 3) * 4;
                *reinterpret_cast<u32*>(Pw + bo) = cvt_pk_bf16(e[0][r], e[1][r]);
            }
            pfl = *reinterpret_cast<const bf16x8*>(Pw + lr * 64 + ((lq ^ (lr & 3)) << 4));
        }

        // ---- O += P V ; l += P . ones (V rows in kv'-sigma space, this wave's half) ----
        __builtin_amdgcn_s_setprio(1);
        #pragma unroll
        for (int n = 0; n < 8; ++n) {
            int vrow = n * 16 + lr;
            int bv = vrow * 128 + ((half * 64 + lq * 16) ^ ((vrow & 7) << 4));
            bf16x8 vf = *reinterpret_cast<const bf16x8*>(Vb + bv);
            oh[n] = __builtin_amdgcn_mfma_f32_16x16x32_bf16(pfh, vf, oh[n], 0, 0, 0);
            if (lo_act) ol[n] = __builtin_amdgcn_mfma_f32_16x16x32_bf16(pfl, vf, ol[n], 0, 0, 0);
        }
        lsh = __builtin_amdgcn_mfma_f32_16x16x32_bf16(pfh, ones, lsh, 0, 0, 0);
        if (lo_act) lsl = __builtin_amdgcn_mfma_f32_16x16x32_bf16(pfl, ones, lsl, 0, 0, 0);
        __builtin_amdgcn_s_setprio(0);
        cur ^= 1;
    }

    // ---- epilogue: combine kv halves via LDS (alias dead K/V bufs), normalize, store ----
    __syncthreads();
    float* Osh = (float*)smem;                   // [4 pairs][2 hi/lo][16 rows][128] f32 = 64KB
    float* Lsh = (float*)(smem + 65536);         // [4][2][16] f32
    if (half == 1) {
        #pragma unroll
        for (int n = 0; n < 8; ++n)
            #pragma unroll
            for (int r = 0; r < 4; ++r) {
                int row = lq * 4 + r, col = n * 16 + lr;
                Osh[(wq * 32 + row) * 128 + col] = oh[n][r];
                Osh[(wq * 32 + 16 + row) * 128 + col] = ol[n][r];
            }
        if (lr == 0) {
            #pragma unroll
            for (int r = 0; r < 4; ++r) {
                Lsh[wq * 32 + lq * 4 + r] = lsh[r];
                Lsh[wq * 32 + 16 + lq * 4 + r] = lsl[r];
            }
        }
    }
    __syncthreads();
    if (half == 0) {
        float invh[4], invl[4];
        #pragma unroll
        for (int r = 0; r < 4; ++r) {
            invh[r] = 1.f / (lsh[r] + Lsh[wq * 32 + lq * 4 + r]);
            invl[r] = 1.f / (lsl[r] + Lsh[wq * 32 + 16 + lq * 4 + r]);
        }
        const size_t obase = ((size_t)b * Tt) * EMB + (size_t)h * HD;
        #pragma unroll
        for (int n = 0; n < 8; ++n)
            #pragma unroll
            for (int r = 0; r < 4; ++r) {
                int row = lq * 4 + r, col = n * 16 + lr;
                float vh = oh[n][r] + Osh[(wq * 32 + row) * 128 + col];
                float vl = ol[n][r] + Osh[(wq * 32 + 16 + row) * 128 + col];
                int rh = ihi * 64 + wq * 16 + row;
                int rl = ilo * 64 + wq * 16 + row;
                Out[obase + (size_t)rh * EMB + col] = f2bf(vh * invh[r]);
                Out[obase + (size_t)rl * EMB + col] = f2bf(vl * invl[r]);
            }
    }
}

// ---------------- launcher ----------------
extern "C" void kernel_launch(void* const* d_in, const int* in_sizes, int n_in,
                              void* d_out, int out_size, void* d_ws, size_t ws_size,
                              hipStream_t stream) {
    (void)in_sizes; (void)n_in; (void)out_size; (void)ws_size;
    const float* x  = (const float*)d_in[0];
    const float* Wq = (const float*)d_in[1];
    const float* Wk = (const float*)d_in[2];
    const float* Wv = (const float*)d_in[3];
    const float* Wo = (const float*)d_in[4];
    float* out = (float*)d_out;

    char* ws = (char*)d_ws;
    size_t off = 0;
    auto alloc = [&](size_t bytes) { char* p = ws + off; off += (bytes + 255) & ~(size_t)255; return p; };

    u16* w_bf    = (u16*)alloc((size_t)(QKVN * EMB + EMB * EMB) * 2);  // Wq|Wk|Wv then Wo
    u16* x_bf    = (u16*)alloc((size_t)MROWS * EMB * 2);
    float* qkv_lin = (float*)alloc((size_t)MROWS * QKVN * 4);
    u16* Qb      = (u16*)alloc((size_t)Bb * NHq * Tt * HD * 2);
    u16* Kb      = (u16*)alloc((size_t)Bb * NGk * Tt * HD * 2);
    u16* Vtb     = (u16*)alloc((size_t)Bb * NGk * HD * Tt * 2);
    float* ctab  = (float*)alloc((size_t)Tt * 64 * 4);
    float* stab  = (float*)alloc((size_t)Tt * 64 * 4);
    u16* attnout = (u16*)qkv_lin;   // alias: qkv_lin dead after rope/vtrans

    u16* wq_bf = w_bf;
    u16* wk_bf = w_bf + (size_t)EMB * EMB;
    u16* wv_bf = wk_bf + (size_t)NGk * HD * EMB;
    u16* wo_bf = wv_bf + (size_t)NGk * HD * EMB;

    // 1. casts
    cast_bf16_kernel<<<(MROWS * EMB / 4 + 255) / 256, 256, 0, stream>>>(x, x_bf, MROWS * EMB / 4);
    cast_bf16_kernel<<<(EMB * EMB / 4 + 255) / 256, 256, 0, stream>>>(Wq, wq_bf, EMB * EMB / 4);
    cast_bf16_kernel<<<(NGk * HD * EMB / 4 + 255) / 256, 256, 0, stream>>>(Wk, wk_bf, NGk * HD * EMB / 4);
    cast_bf16_kernel<<<(NGk * HD * EMB / 4 + 255) / 256, 256, 0, stream>>>(Wv, wv_bf, NGk * HD * EMB / 4);
    cast_bf16_kernel<<<(EMB * EMB / 4 + 255) / 256, 256, 0, stream>>>(Wo, wo_bf, EMB * EMB / 4);
    rope_tables_kernel<<<Tt, 64, 0, stream>>>(ctab, stab);

    // 2. fused QKV projection: qkv_lin[4096][3072] = x_bf @ [Wq;Wk;Wv]^T
    gemm_bt<<<dim3(MROWS / 128, QKVN / 128), 256, 0, stream>>>(x_bf, w_bf, qkv_lin, MROWS, QKVN, EMB);

    // 3. RoPE + relayout (+ fold softmax scale*log2e into Q)
    const float qscale = 1.44269504088896f / sqrtf((float)HD);
    rope_kernel<<<dim3(Tt / 4, NHq, Bb), dim3(64, 4), 0, stream>>>(qkv_lin, ctab, stab, Qb, 0, NHq, qscale);
    rope_kernel<<<dim3(Tt / 4, NGk, Bb), dim3(64, 4), 0, stream>>>(qkv_lin, ctab, stab, Kb, EMB, NGk, 1.0f);
    vtrans_kernel<<<dim3(Tt / 64, NGk, Bb), dim3(64, 8), 0, stream>>>(qkv_lin, Vtb);

    // 4. flash attention (8-wave kv-split) -> attnout bf16 [B][T][EMB]
    flash_attn<<<dim3(NQT / 2, NHq, Bb), 512, 0, stream>>>(Qb, Kb, Vtb, attnout);

    // 5. output projection: out = attnout @ Wo^T  (f32 out)
    gemm_bt<<<dim3(MROWS / 128, EMB / 128), 256, 0, stream>>>(attnout, wo_bf, out, MROWS, EMB, EMB);
}

// Round 8
// 250.562 us; speedup vs baseline: 1.2054x; 1.0652x over previous
//
#include <hip/hip_runtime.h>
#include <stdint.h>
#include <math.h>

#define EMB 2048
#define NHq 16
#define NGk 4
#define HD 128
#define Bb 2
#define Tt 2048
#define MROWS (Bb*Tt)      // 4096
#define QKVN 3072          // 2048 q + 512 k + 512 v
#define NQT 32             // q-tiles of 64 rows per (b,h)

typedef __bf16 bf16x8 __attribute__((ext_vector_type(8)));
typedef float f32x4 __attribute__((ext_vector_type(4)));
typedef unsigned short u16;
typedef unsigned int u32;

__device__ __forceinline__ u16 f2bf(float f) {
    unsigned int u = __float_as_uint(f);
    u += 0x7fff + ((u >> 16) & 1);          // round-to-nearest-even
    return (u16)(u >> 16);
}
__device__ __forceinline__ float bf2f(u16 u) {
    return __uint_as_float(((u32)u) << 16);
}
__device__ __forceinline__ u32 cvt_pk_bf16(float lo, float hi) {
    u32 r;
    asm("v_cvt_pk_bf16_f32 %0, %1, %2" : "=v"(r) : "v"(lo), "v"(hi));
    return r;
}

#define GLOAD_LDS16(g, l) \
    __builtin_amdgcn_global_load_lds((const __attribute__((address_space(1))) void*)(g), \
                                     (__attribute__((address_space(3))) void*)(l), 16, 0, 0)

// ---------------- cast f32 -> bf16, vectorized ----------------
__global__ void cast_bf16_kernel(const float* __restrict__ src, u16* __restrict__ dst, int n4) {
    int i = blockIdx.x * blockDim.x + threadIdx.x;
    if (i < n4) {
        float4 v = reinterpret_cast<const float4*>(src)[i];
        ushort4 o;
        o.x = f2bf(v.x); o.y = f2bf(v.y); o.z = f2bf(v.z); o.w = f2bf(v.w);
        reinterpret_cast<ushort4*>(dst)[i] = o;
    }
}

// ---------------- fused weight cast: Wq|Wk|Wv|Wo -> contiguous bf16 ----------------
__global__ void wcast_kernel(const float* __restrict__ Wq, const float* __restrict__ Wk,
                             const float* __restrict__ Wv, const float* __restrict__ Wo,
                             u16* __restrict__ dst) {
    int i = blockIdx.x * blockDim.x + threadIdx.x;     // float4 chunk index, 2621440 total
    const float* src; int local;
    if (i < 1048576)      { src = Wq; local = i; }
    else if (i < 1310720) { src = Wk; local = i - 1048576; }
    else if (i < 1572864) { src = Wv; local = i - 1310720; }
    else                  { src = Wo; local = i - 1572864; }
    float4 v = reinterpret_cast<const float4*>(src)[local];
    ushort4 o;
    o.x = f2bf(v.x); o.y = f2bf(v.y); o.z = f2bf(v.z); o.w = f2bf(v.w);
    reinterpret_cast<ushort4*>(dst)[i] = o;
}

// ---------------- RoPE cos/sin tables: [T][64] ----------------
__global__ void rope_tables_kernel(float* __restrict__ ctab, float* __restrict__ stab) {
    int t = blockIdx.x, i = threadIdx.x;     // grid T, block 64
    float inv = powf(10000.f, -2.f * (float)i / (float)HD);
    float ang = (float)t * inv;
    ctab[t * 64 + i] = cosf(ang);
    stab[t * 64 + i] = sinf(ang);
}

// ---------------- fused RoPE q+k: lin[M][3072] bf16 -> Qb / Kb bf16 ----------------
__global__ void rope_qk_kernel(const u16* __restrict__ lin, const float* __restrict__ ctab,
                               const float* __restrict__ stab, u16* __restrict__ Qb,
                               u16* __restrict__ Kb, float qscale) {
    // grid (T/4, NHq+NGk, B), block (64,4)
    int i = threadIdx.x;                       // pair index 0..63
    int tt = blockIdx.x * 4 + threadIdx.y;
    int hh = blockIdx.y, b = blockIdx.z;
    int coloff; u16* out; float scale;
    if (hh < NHq) { coloff = hh * HD; scale = qscale;
                    out = Qb + (((size_t)(b * NHq + hh)) * Tt + tt) * HD; }
    else { int g = hh - NHq; coloff = EMB + g * HD; scale = 1.f;
           out = Kb + (((size_t)(b * NGk + g)) * Tt + tt) * HD; }
    u32 pair = *reinterpret_cast<const u32*>(&lin[((size_t)(b * Tt + tt)) * QKVN + coloff + 2 * i]);
    float x1 = bf2f((u16)(pair & 0xffff)), x2 = bf2f((u16)(pair >> 16));
    float c = ctab[tt * 64 + i], s = stab[tt * 64 + i];
    ushort2 o;
    o.x = f2bf((x1 * c - x2 * s) * scale);
    o.y = f2bf((x1 * s + x2 * c) * scale);
    *reinterpret_cast<ushort2*>(&out[2 * i]) = o;
}

// ---------------- V relayout+transpose (bf16 copy): lin -> Vt[B][NG][HD][T], kk-PERMUTED ----------------
// Within each 32-kv tile, kv index c stored at sigma(c) = (c&15)*2 + (c>>4)  (matches packed P-store).
__global__ void vtrans_kernel(const u16* __restrict__ lin, u16* __restrict__ vt) {
    // grid (T/64, NG, B), block (64,8)
    int tx = threadIdx.x, dy = threadIdx.y;
    int tt = blockIdx.x * 64 + tx;
    int g = blockIdx.y, b = blockIdx.z;
    int ttp = (tt & ~31) | (((tt & 15) << 1) | ((tt >> 4) & 1));   // permuted position
    const u16* src = &lin[((size_t)(b * Tt + tt)) * QKVN + EMB + NGk * HD + g * HD];
    u16* dst = &vt[(((size_t)(b * NGk + g)) * HD) * Tt + ttp];
    #pragma unroll
    for (int k = 0; k < 16; ++k) {
        int d = dy + k * 8;
        dst[(size_t)d * Tt] = src[d];
    }
}

// ---------------- bf16 GEMM: C[M][N] = A[M][K]bf16 @ W[N][K]bf16 ^T, OutT f32 or bf16 ----------------
template<int OUTBF>
__global__ __launch_bounds__(256) void gemm_bt(const u16* __restrict__ A, const u16* __restrict__ W,
                                               void* __restrict__ Cout, int M, int N, int K) {
    __shared__ u16 Atile[128 * 32];
    __shared__ u16 Btile[128 * 32];
    const int brow = blockIdx.x * 128;
    const int bcol = blockIdx.y * 128;
    const int t = threadIdx.x;
    const int w = t >> 6, l = t & 63;
    const int lr = l & 15, lq = l >> 4;
    const int wr = (w >> 1) * 64, wc = (w & 1) * 64;
    f32x4 acc[4][4] = {};
    const int nkt = K >> 5;
    for (int kt = 0; kt < nkt; ++kt) {
        const int k0 = kt * 32;
        #pragma unroll
        for (int i = 0; i < 2; ++i) {
            int f = i * 256 + t;
            int row = f >> 2, cb = (f & 3) * 8;
            GLOAD_LDS16(A + (size_t)(brow + row) * K + k0 + cb, &Atile[(i * 256 + w * 64) * 8]);
            GLOAD_LDS16(W + (size_t)(bcol + row) * K + k0 + cb, &Btile[(i * 256 + w * 64) * 8]);
        }
        __syncthreads();
        bf16x8 a[4], b[4];
        #pragma unroll
        for (int m = 0; m < 4; ++m)
            a[m] = *reinterpret_cast<const bf16x8*>(&Atile[(wr + m * 16 + lr) * 32 + lq * 8]);
        #pragma unroll
        for (int n = 0; n < 4; ++n)
            b[n] = *reinterpret_cast<const bf16x8*>(&Btile[(wc + n * 16 + lr) * 32 + lq * 8]);
        #pragma unroll
        for (int m = 0; m < 4; ++m)
            #pragma unroll
            for (int n = 0; n < 4; ++n)
                acc[m][n] = __builtin_amdgcn_mfma_f32_16x16x32_bf16(a[m], b[n], acc[m][n], 0, 0, 0);
        __syncthreads();
    }
    #pragma unroll
    for (int m = 0; m < 4; ++m)
        #pragma unroll
        for (int n = 0; n < 4; ++n)
            #pragma unroll
            for (int r = 0; r < 4; ++r) {
                size_t idx = (size_t)(brow + wr + m * 16 + lq * 4 + r) * N + bcol + wc + n * 16 + lr;
                if (OUTBF) ((u16*)Cout)[idx] = f2bf(acc[m][n][r]);
                else       ((float*)Cout)[idx] = acc[m][n][r];
            }
}

// ---------------- flash attention v8: 8 waves, kv-half split, CU-balanced diagonal pairing ----------------
// Block = diagonal pair {ilo, 31-ilo}; ilo flipped by batch (b==0: bx, b==1: 15-bx) so that
// co-resident blocks (ids k and k+256 differ only in z) have COMPLEMENTARY round counts
// (17+32 everywhere) -> balanced per-CU makespan.
// Waves 0-3 handle kv[0..31], waves 4-7 kv[32..63]; fixed-shift softmax (no running max)
// makes halves trivially combinable at the epilogue via one LDS exchange.
__global__ __launch_bounds__(512) void flash_attn(const u16* __restrict__ Q, const u16* __restrict__ K,
                                                  const u16* __restrict__ Vt, u16* __restrict__ Out) {
    __shared__ __align__(16) char smem[73728];   // K 2x16K | V 2x16K | P 8x1K
    u16* KldsBase = (u16*)smem;
    u16* VldsBase = (u16*)(smem + 32768);
    const int h = blockIdx.y;
    const int b = blockIdx.z;
    const int ilo = (b == 0) ? blockIdx.x : (NQT / 2 - 1 - blockIdx.x);   // 0..15
    const int ihi = NQT - 1 - ilo;        // 16..31
    const int g = h >> 2;
    const int t = threadIdx.x;
    const int w = t >> 6, l = t & 63;
    const int wq = w & 3, half = w >> 2;
    const int lr = l & 15, lq = l >> 4;
    char* Pw = smem + 65536 + w * 1024;   // per-wave P tile [16 q][32 kv'] bf16, slot-swizzled

    // Q fragments: 16 rows of lo tile + 16 rows of hi tile (wave pairs w, w+4 share rows)
    const size_t qhead = ((size_t)(b * NHq + h)) * Tt;
    const size_t qblo = (qhead + ilo * 64 + wq * 16) * HD;
    const size_t qbhi = (qhead + ihi * 64 + wq * 16) * HD;
    bf16x8 qfl[4], qfh[4];
    #pragma unroll
    for (int d = 0; d < 4; ++d) {
        qfl[d] = *reinterpret_cast<const bf16x8*>(&Q[qblo + (size_t)lr * HD + d * 32 + lq * 8]);
        qfh[d] = *reinterpret_cast<const bf16x8*>(&Q[qbhi + (size_t)lr * HD + d * 32 + lq * 8]);
    }
    bf16x8 ones;
    #pragma unroll
    for (int j = 0; j < 8; ++j) ones[j] = (__bf16)1.0f;

    f32x4 ol[8] = {}, oh[8] = {};
    f32x4 lsl = {}, lsh = {};

    const int qlo0 = ilo * 64 + wq * 16 + lq * 4;
    const int qhi0 = ihi * 64 + wq * 16 + lq * 4;
    const size_t kbase  = ((size_t)(b * NGk + g)) * Tt * HD;
    const size_t vtbase = ((size_t)(b * NGk + g)) * HD * Tt;
    const int nkt = NQT - ilo;            // 17..32 staged tiles

    // staging: 512 threads x 2 chunks of 16B per operand per tile; source pre-swizzled
    // by ^(row&7) so linear gload_lds dest yields the swizzled read layout (rule #21).
    int kofs[2], vofs[2];
    #pragma unroll
    for (int j = 0; j < 2; ++j) {
        int krow = j * 32 + w * 4 + (l >> 4);
        kofs[j] = krow * HD + (((l & 15) ^ (krow & 7)) * 8);
        int vrow = j * 64 + w * 8 + (l >> 3);
        vofs[j] = vrow * (int)Tt + (((l & 7) ^ (vrow & 7)) * 8);
    }

    // prologue: stage tile 0 into buf 0
    #pragma unroll
    for (int j = 0; j < 2; ++j) {
        GLOAD_LDS16(K + kbase + kofs[j], KldsBase + (j * 512 + w * 64) * 8);
        GLOAD_LDS16(Vt + vtbase + vofs[j], VldsBase + (j * 512 + w * 64) * 8);
    }
    int cur = 0;

    for (int kt = 0; kt < nkt; ++kt) {
        const int kp0 = kt * 64;
        __syncthreads();                      // tile kt resident in buf[cur]
        if (kt + 1 < nkt) {                   // issue next tile -> buf[cur^1]
            #pragma unroll
            for (int j = 0; j < 2; ++j) {
                GLOAD_LDS16(K + kbase + (size_t)(kp0 + 64) * HD + kofs[j],
                            KldsBase + (cur ^ 1) * 8192 + (j * 512 + w * 64) * 8);
                GLOAD_LDS16(Vt + vtbase + (kp0 + 64) + vofs[j],
                            VldsBase + (cur ^ 1) * 8192 + (j * 512 + w * 64) * 8);
            }
        }
        const char* Kb = smem + cur * 16384;
        const char* Vb = smem + 32768 + cur * 16384;

        const bool lo_act = (kt <= ilo);
        // ---- S = Q K^T over this wave's kv half (2 col-tiles of 16) ----
        f32x4 sl[2] = {}, sh[2] = {};
        __builtin_amdgcn_s_setprio(1);
        #pragma unroll
        for (int ct = 0; ct < 2; ++ct) {
            #pragma unroll
            for (int d = 0; d < 4; ++d) {
                int row = half * 32 + ct * 16 + lr;
                int bo = row * 256 + ((d * 64 + lq * 16) ^ ((row & 7) << 4));
                bf16x8 kf = *reinterpret_cast<const bf16x8*>(Kb + bo);
                if (lo_act) sl[ct] = __builtin_amdgcn_mfma_f32_16x16x32_bf16(qfl[d], kf, sl[ct], 0, 0, 0);
                sh[ct] = __builtin_amdgcn_mfma_f32_16x16x32_bf16(qfh[d], kf, sh[ct], 0, 0, 0);
            }
        }
        __builtin_amdgcn_s_setprio(0);

        // ---- fixed-shift softmax, packed P-store (slot-swizzled, conflict-free read) ----
        {   // hi half (always active)
            const bool diag = (kt == nkt - 1);
            float e[2][4];
            #pragma unroll
            for (int ct = 0; ct < 2; ++ct)
                #pragma unroll
                for (int r = 0; r < 4; ++r) {
                    float v = sh[ct][r];
                    if (diag && (kp0 + half * 32 + ct * 16 + lr > qhi0 + r)) v = -1e30f;
                    e[ct][r] = exp2f(v);
                }
            #pragma unroll
            for (int r = 0; r < 4; ++r) {
                int row = lq * 4 + r;
                int bo = row * 64 + (((lr >> 2) ^ (row & 3)) << 4) + (lr & 3) * 4;
                *reinterpret_cast<u32*>(Pw + bo) = cvt_pk_bf16(e[0][r], e[1][r]);
            }
        }
        bf16x8 pfh = *reinterpret_cast<const bf16x8*>(Pw + lr * 64 + ((lq ^ (lr & 3)) << 4));
        bf16x8 pfl;
        if (lo_act) {
            const bool diag = (kt == ilo);
            float e[2][4];
            #pragma unroll
            for (int ct = 0; ct < 2; ++ct)
                #pragma unroll
                for (int r = 0; r < 4; ++r) {
                    float v = sl[ct][r];
                    if (diag && (kp0 + half * 32 + ct * 16 + lr > qlo0 + r)) v = -1e30f;
                    e[ct][r] = exp2f(v);
                }
            #pragma unroll
            for (int r = 0; r < 4; ++r) {
                int row = lq * 4 + r;
                int bo = row * 64 + (((lr >> 2) ^ (row & 3)) << 4) + (lr & 3) * 4;
                *reinterpret_cast<u32*>(Pw + bo) = cvt_pk_bf16(e[0][r], e[1][r]);
            }
            pfl = *reinterpret_cast<const bf16x8*>(Pw + lr * 64 + ((lq ^ (lr & 3)) << 4));
        }

        // ---- O += P V ; l += P . ones (V rows in kv'-sigma space, this wave's half) ----
        __builtin_amdgcn_s_setprio(1);
        #pragma unroll
        for (int n = 0; n < 8; ++n) {
            int vrow = n * 16 + lr;
            int bv = vrow * 128 + ((half * 64 + lq * 16) ^ ((vrow & 7) << 4));
            bf16x8 vf = *reinterpret_cast<const bf16x8*>(Vb + bv);
            oh[n] = __builtin_amdgcn_mfma_f32_16x16x32_bf16(pfh, vf, oh[n], 0, 0, 0);
            if (lo_act) ol[n] = __builtin_amdgcn_mfma_f32_16x16x32_bf16(pfl, vf, ol[n], 0, 0, 0);
        }
        lsh = __builtin_amdgcn_mfma_f32_16x16x32_bf16(pfh, ones, lsh, 0, 0, 0);
        if (lo_act) lsl = __builtin_amdgcn_mfma_f32_16x16x32_bf16(pfl, ones, lsl, 0, 0, 0);
        __builtin_amdgcn_s_setprio(0);
        cur ^= 1;
    }

    // ---- epilogue: combine kv halves via LDS (alias dead K/V bufs), normalize, store ----
    __syncthreads();
    float* Osh = (float*)smem;                   // [4 pairs][2 hi/lo][16 rows][128] f32 = 64KB
    float* Lsh = (float*)(smem + 65536);         // [4][2][16] f32
    if (half == 1) {
        #pragma unroll
        for (int n = 0; n < 8; ++n)
            #pragma unroll
            for (int r = 0; r < 4; ++r) {
                int row = lq * 4 + r, col = n * 16 + lr;
                Osh[(wq * 32 + row) * 128 + col] = oh[n][r];
                Osh[(wq * 32 + 16 + row) * 128 + col] = ol[n][r];
            }
        if (lr == 0) {
            #pragma unroll
            for (int r = 0; r < 4; ++r) {
                Lsh[wq * 32 + lq * 4 + r] = lsh[r];
                Lsh[wq * 32 + 16 + lq * 4 + r] = lsl[r];
            }
        }
    }
    __syncthreads();
    if (half == 0) {
        float invh[4], invl[4];
        #pragma unroll
        for (int r = 0; r < 4; ++r) {
            invh[r] = 1.f / (lsh[r] + Lsh[wq * 32 + lq * 4 + r]);
            invl[r] = 1.f / (lsl[r] + Lsh[wq * 32 + 16 + lq * 4 + r]);
        }
        const size_t obase = ((size_t)b * Tt) * EMB + (size_t)h * HD;
        #pragma unroll
        for (int n = 0; n < 8; ++n)
            #pragma unroll
            for (int r = 0; r < 4; ++r) {
                int row = lq * 4 + r, col = n * 16 + lr;
                float vh = oh[n][r] + Osh[(wq * 32 + row) * 128 + col];
                float vl = ol[n][r] + Osh[(wq * 32 + 16 + row) * 128 + col];
                int rh = ihi * 64 + wq * 16 + row;
                int rl = ilo * 64 + wq * 16 + row;
                Out[obase + (size_t)rh * EMB + col] = f2bf(vh * invh[r]);
                Out[obase + (size_t)rl * EMB + col] = f2bf(vl * invl[r]);
            }
    }
}

// ---------------- launcher ----------------
extern "C" void kernel_launch(void* const* d_in, const int* in_sizes, int n_in,
                              void* d_out, int out_size, void* d_ws, size_t ws_size,
                              hipStream_t stream) {
    (void)in_sizes; (void)n_in; (void)out_size; (void)ws_size;
    const float* x  = (const float*)d_in[0];
    const float* Wq = (const float*)d_in[1];
    const float* Wk = (const float*)d_in[2];
    const float* Wv = (const float*)d_in[3];
    const float* Wo = (const float*)d_in[4];
    float* out = (float*)d_out;

    char* ws = (char*)d_ws;
    size_t off = 0;
    auto alloc = [&](size_t bytes) { char* p = ws + off; off += (bytes + 255) & ~(size_t)255; return p; };

    u16* w_bf    = (u16*)alloc((size_t)(QKVN * EMB + EMB * EMB) * 2);  // Wq|Wk|Wv then Wo
    u16* x_bf    = (u16*)alloc((size_t)MROWS * EMB * 2);
    u16* qkv_lin = (u16*)alloc((size_t)MROWS * QKVN * 4);              // bf16 used; f32-size kept
    u16* Qb      = (u16*)alloc((size_t)Bb * NHq * Tt * HD * 2);
    u16* Kb      = (u16*)alloc((size_t)Bb * NGk * Tt * HD * 2);
    u16* Vtb     = (u16*)alloc((size_t)Bb * NGk * HD * Tt * 2);
    float* ctab  = (float*)alloc((size_t)Tt * 64 * 4);
    float* stab  = (float*)alloc((size_t)Tt * 64 * 4);
    u16* attnout = qkv_lin;         // alias: qkv_lin dead after rope/vtrans

    u16* wo_bf = w_bf + (size_t)QKVN * EMB;

    // 1. casts (x + fused weights) + tables
    cast_bf16_kernel<<<(MROWS * EMB / 4 + 255) / 256, 256, 0, stream>>>(x, x_bf, MROWS * EMB / 4);
    wcast_kernel<<<(QKVN * EMB + EMB * EMB) / 4 / 256, 256, 0, stream>>>(Wq, Wk, Wv, Wo, w_bf);
    rope_tables_kernel<<<Tt, 64, 0, stream>>>(ctab, stab);

    // 2. fused QKV projection: qkv_lin[4096][3072] bf16 = x_bf @ [Wq;Wk;Wv]^T
    gemm_bt<1><<<dim3(MROWS / 128, QKVN / 128), 256, 0, stream>>>(x_bf, w_bf, qkv_lin, MROWS, QKVN, EMB);

    // 3. RoPE q+k (fused) + V transpose (+ fold softmax scale*log2e into Q)
    const float qscale = 1.44269504088896f / sqrtf((float)HD);
    rope_qk_kernel<<<dim3(Tt / 4, NHq + NGk, Bb), dim3(64, 4), 0, stream>>>(qkv_lin, ctab, stab, Qb, Kb, qscale);
    vtrans_kernel<<<dim3(Tt / 64, NGk, Bb), dim3(64, 8), 0, stream>>>(qkv_lin, Vtb);

    // 4. flash attention (8-wave kv-split, CU-balanced) -> attnout bf16 [B][T][EMB]
    flash_attn<<<dim3(NQT / 2, NHq, Bb), 512, 0, stream>>>(Qb, Kb, Vtb, attnout);

    // 5. output projection: out = attnout @ Wo^T  (f32 out)
    gemm_bt<0><<<dim3(MROWS / 128, EMB / 128), 256, 0, stream>>>(attnout, wo_bf, out, MROWS, EMB, EMB);
}

// Round 9
// 240.660 us; speedup vs baseline: 1.2550x; 1.0411x over previous
//
#include <hip/hip_runtime.h>
#include <stdint.h>
#include <math.h>

#define EMB 2048
#define NHq 16
#define NGk 4
#define HD 128
#define Bb 2
#define Tt 2048
#define MROWS (Bb*Tt)      // 4096
#define QKVN 3072          // 2048 q + 512 k + 512 v
#define NQT 32             // q-tiles of 64 rows per (b,h)

typedef __bf16 bf16x8 __attribute__((ext_vector_type(8)));
typedef float f32x4 __attribute__((ext_vector_type(4)));
typedef unsigned int u32x4 __attribute__((ext_vector_type(4)));
typedef unsigned short u16;
typedef unsigned int u32;

__device__ __forceinline__ u16 f2bf(float f) {
    unsigned int u = __float_as_uint(f);
    u += 0x7fff + ((u >> 16) & 1);          // round-to-nearest-even
    return (u16)(u >> 16);
}
__device__ __forceinline__ float bf2f(u16 u) {
    return __uint_as_float(((u32)u) << 16);
}
__device__ __forceinline__ u32 cvt_pk_bf16(float lo, float hi) {
    u32 r;
    asm("v_cvt_pk_bf16_f32 %0, %1, %2" : "=v"(r) : "v"(lo), "v"(hi));
    return r;
}

#define GLOAD_LDS16(g, l) \
    __builtin_amdgcn_global_load_lds((const __attribute__((address_space(1))) void*)(g), \
                                     (__attribute__((address_space(3))) void*)(l), 16, 0, 0)

// ---------------- cast f32 -> bf16, vectorized ----------------
__global__ void cast_bf16_kernel(const float* __restrict__ src, u16* __restrict__ dst, int n4) {
    int i = blockIdx.x * blockDim.x + threadIdx.x;
    if (i < n4) {
        float4 v = reinterpret_cast<const float4*>(src)[i];
        ushort4 o;
        o.x = f2bf(v.x); o.y = f2bf(v.y); o.z = f2bf(v.z); o.w = f2bf(v.w);
        reinterpret_cast<ushort4*>(dst)[i] = o;
    }
}

// ---------------- fused weight cast: Wq|Wk|Wv|Wo -> contiguous bf16 ----------------
__global__ void wcast_kernel(const float* __restrict__ Wq, const float* __restrict__ Wk,
                             const float* __restrict__ Wv, const float* __restrict__ Wo,
                             u16* __restrict__ dst) {
    int i = blockIdx.x * blockDim.x + threadIdx.x;     // float4 chunk index, 2621440 total
    const float* src; int local;
    if (i < 1048576)      { src = Wq; local = i; }
    else if (i < 1310720) { src = Wk; local = i - 1048576; }
    else if (i < 1572864) { src = Wv; local = i - 1310720; }
    else                  { src = Wo; local = i - 1572864; }
    float4 v = reinterpret_cast<const float4*>(src)[local];
    ushort4 o;
    o.x = f2bf(v.x); o.y = f2bf(v.y); o.z = f2bf(v.z); o.w = f2bf(v.w);
    reinterpret_cast<ushort4*>(dst)[i] = o;
}

// ---------------- RoPE cos/sin tables: [T][64] ----------------
__global__ void rope_tables_kernel(float* __restrict__ ctab, float* __restrict__ stab) {
    int t = blockIdx.x, i = threadIdx.x;     // grid T, block 64
    float inv = powf(10000.f, -2.f * (float)i / (float)HD);
    float ang = (float)t * inv;
    ctab[t * 64 + i] = cosf(ang);
    stab[t * 64 + i] = sinf(ang);
}

// ---------------- fused RoPE q+k: lin[M][3072] bf16 -> Qb / Kb bf16 ----------------
__global__ void rope_qk_kernel(const u16* __restrict__ lin, const float* __restrict__ ctab,
                               const float* __restrict__ stab, u16* __restrict__ Qb,
                               u16* __restrict__ Kb, float qscale) {
    // grid (T/4, NHq+NGk, B), block (64,4)
    int i = threadIdx.x;                       // pair index 0..63
    int tt = blockIdx.x * 4 + threadIdx.y;
    int hh = blockIdx.y, b = blockIdx.z;
    int coloff; u16* out; float scale;
    if (hh < NHq) { coloff = hh * HD; scale = qscale;
                    out = Qb + (((size_t)(b * NHq + hh)) * Tt + tt) * HD; }
    else { int g = hh - NHq; coloff = EMB + g * HD; scale = 1.f;
           out = Kb + (((size_t)(b * NGk + g)) * Tt + tt) * HD; }
    u32 pair = *reinterpret_cast<const u32*>(&lin[((size_t)(b * Tt + tt)) * QKVN + coloff + 2 * i]);
    float x1 = bf2f((u16)(pair & 0xffff)), x2 = bf2f((u16)(pair >> 16));
    float c = ctab[tt * 64 + i], s = stab[tt * 64 + i];
    ushort2 o;
    o.x = f2bf((x1 * c - x2 * s) * scale);
    o.y = f2bf((x1 * s + x2 * c) * scale);
    *reinterpret_cast<ushort2*>(&out[2 * i]) = o;
}

// ---------------- V relayout+transpose (bf16 copy): lin -> Vt[B][NG][HD][T], kv sigma-PERMUTED ----
// PV's B-operand (in-register P from swapped QK^T) delivers, for lane group lq, MFMA-k index
// lq*8+e holding the P value of kv = sigma(lq*8+e) = lq*4 + (e&3) + 16*(e>>2) (within each
// 32-kv half). Store V row for MFMA-k position k at kv sigma(k): position of kv c is
// sigma^-1(c) = ((c>>2)&3)*8 + ((c>>4)&1)*4 + (c&3).
__global__ void vtrans_kernel(const u16* __restrict__ lin, u16* __restrict__ vt) {
    // grid (T/64, NG, B), block (64,8)
    int tx = threadIdx.x, dy = threadIdx.y;
    int tt = blockIdx.x * 64 + tx;
    int g = blockIdx.y, b = blockIdx.z;
    int ttp = (tt & ~31) | (((tt >> 2) & 3) * 8 + ((tt >> 4) & 1) * 4 + (tt & 3));
    const u16* src = &lin[((size_t)(b * Tt + tt)) * QKVN + EMB + NGk * HD + g * HD];
    u16* dst = &vt[(((size_t)(b * NGk + g)) * HD) * Tt + ttp];
    #pragma unroll
    for (int k = 0; k < 16; ++k) {
        int d = dy + k * 8;
        dst[(size_t)d * Tt] = src[d];
    }
}

// ---------------- bf16 GEMM: C[M][N] = A[M][K]bf16 @ W[N][K]bf16 ^T, OutT f32 or bf16 ----------------
template<int OUTBF>
__global__ __launch_bounds__(256) void gemm_bt(const u16* __restrict__ A, const u16* __restrict__ W,
                                               void* __restrict__ Cout, int M, int N, int K) {
    __shared__ u16 Atile[128 * 32];
    __shared__ u16 Btile[128 * 32];
    const int brow = blockIdx.x * 128;
    const int bcol = blockIdx.y * 128;
    const int t = threadIdx.x;
    const int w = t >> 6, l = t & 63;
    const int lr = l & 15, lq = l >> 4;
    const int wr = (w >> 1) * 64, wc = (w & 1) * 64;
    f32x4 acc[4][4] = {};
    const int nkt = K >> 5;
    for (int kt = 0; kt < nkt; ++kt) {
        const int k0 = kt * 32;
        #pragma unroll
        for (int i = 0; i < 2; ++i) {
            int f = i * 256 + t;
            int row = f >> 2, cb = (f & 3) * 8;
            GLOAD_LDS16(A + (size_t)(brow + row) * K + k0 + cb, &Atile[(i * 256 + w * 64) * 8]);
            GLOAD_LDS16(W + (size_t)(bcol + row) * K + k0 + cb, &Btile[(i * 256 + w * 64) * 8]);
        }
        __syncthreads();
        bf16x8 a[4], b[4];
        #pragma unroll
        for (int m = 0; m < 4; ++m)
            a[m] = *reinterpret_cast<const bf16x8*>(&Atile[(wr + m * 16 + lr) * 32 + lq * 8]);
        #pragma unroll
        for (int n = 0; n < 4; ++n)
            b[n] = *reinterpret_cast<const bf16x8*>(&Btile[(wc + n * 16 + lr) * 32 + lq * 8]);
        #pragma unroll
        for (int m = 0; m < 4; ++m)
            #pragma unroll
            for (int n = 0; n < 4; ++n)
                acc[m][n] = __builtin_amdgcn_mfma_f32_16x16x32_bf16(a[m], b[n], acc[m][n], 0, 0, 0);
        __syncthreads();
    }
    #pragma unroll
    for (int m = 0; m < 4; ++m)
        #pragma unroll
        for (int n = 0; n < 4; ++n)
            #pragma unroll
            for (int r = 0; r < 4; ++r) {
                size_t idx = (size_t)(brow + wr + m * 16 + lq * 4 + r) * N + bcol + wc + n * 16 + lr;
                if (OUTBF) ((u16*)Cout)[idx] = f2bf(acc[m][n][r]);
                else       ((float*)Cout)[idx] = acc[m][n][r];
            }
}

// ---------------- flash attention v9: swapped QK^T, in-register P (no P-LDS) ----------------
// mfma(K,Q) puts S^T in registers: lane (lr,lq) holds, for q-row (group+lr), S at kv
// (ct*16 + lq*4 + r). exp2 + cvt_pk yields the PV B-fragment DIRECTLY (V's kv rows are
// sigma-permuted to match, see vtrans) -> the P LDS round trip is gone entirely.
// Block = diagonal pair {ilo, 31-ilo}, 512 thr; waves 0-3 kv[0..31], 4-7 kv[32..63];
// fixed-shift softmax; row-sum l via ones-MFMA (A=ones); kv-halves combined via LDS epilogue.
// Output layout per lane: O[q = group+lr][d = n*16 + lq*4 + r].
__global__ __launch_bounds__(512) void flash_attn(const u16* __restrict__ Q, const u16* __restrict__ K,
                                                  const u16* __restrict__ Vt, u16* __restrict__ Out) {
    __shared__ __align__(16) char smem[69632];   // K 2x16K | V 2x16K ; epilogue Osh/Lsh alias
    u16* KldsBase = (u16*)smem;
    u16* VldsBase = (u16*)(smem + 32768);
    const int h = blockIdx.y;
    const int b = blockIdx.z;
    const int ilo = (b == 0) ? blockIdx.x : (NQT / 2 - 1 - blockIdx.x);   // 0..15
    const int ihi = NQT - 1 - ilo;        // 16..31
    const int g = h >> 2;
    const int t = threadIdx.x;
    const int w = t >> 6, l = t & 63;
    const int wq = w & 3, half = w >> 2;
    const int lr = l & 15, lq = l >> 4;

    // Q fragments (B-operand): lane lr holds Q-row (group+lr), k-slice lq*8 of each 32-d tile
    const size_t qhead = ((size_t)(b * NHq + h)) * Tt;
    const size_t qblo = (qhead + ilo * 64 + wq * 16) * HD;
    const size_t qbhi = (qhead + ihi * 64 + wq * 16) * HD;
    bf16x8 qfl[4], qfh[4];
    #pragma unroll
    for (int d = 0; d < 4; ++d) {
        qfl[d] = *reinterpret_cast<const bf16x8*>(&Q[qblo + (size_t)lr * HD + d * 32 + lq * 8]);
        qfh[d] = *reinterpret_cast<const bf16x8*>(&Q[qbhi + (size_t)lr * HD + d * 32 + lq * 8]);
    }
    bf16x8 ones;
    #pragma unroll
    for (int j = 0; j < 8; ++j) ones[j] = (__bf16)1.0f;

    f32x4 ol[8] = {}, oh[8] = {};
    f32x4 lsl = {}, lsh = {};

    const int qlo = ilo * 64 + wq * 16 + lr;   // this lane's q-row (lo / hi tile)
    const int qhi = ihi * 64 + wq * 16 + lr;
    const size_t kbase  = ((size_t)(b * NGk + g)) * Tt * HD;
    const size_t vtbase = ((size_t)(b * NGk + g)) * HD * Tt;
    const int nkt = NQT - ilo;            // 17..32 staged tiles

    // staging: source pre-swizzled by ^(row&7) so linear gload_lds dest = swizzled layout
    int kofs[2], vofs[2];
    #pragma unroll
    for (int j = 0; j < 2; ++j) {
        int krow = j * 32 + w * 4 + (l >> 4);
        kofs[j] = krow * HD + (((l & 15) ^ (krow & 7)) * 8);
        int vrow = j * 64 + w * 8 + (l >> 3);
        vofs[j] = vrow * (int)Tt + (((l & 7) ^ (vrow & 7)) * 8);
    }

    // prologue: stage tile 0 into buf 0
    #pragma unroll
    for (int j = 0; j < 2; ++j) {
        GLOAD_LDS16(K + kbase + kofs[j], KldsBase + (j * 512 + w * 64) * 8);
        GLOAD_LDS16(Vt + vtbase + vofs[j], VldsBase + (j * 512 + w * 64) * 8);
    }
    int cur = 0;

    for (int kt = 0; kt < nkt; ++kt) {
        const int kp0 = kt * 64;
        __syncthreads();                      // tile kt resident in buf[cur]
        if (kt + 1 < nkt) {                   // issue next tile -> buf[cur^1]
            #pragma unroll
            for (int j = 0; j < 2; ++j) {
                GLOAD_LDS16(K + kbase + (size_t)(kp0 + 64) * HD + kofs[j],
                            KldsBase + (cur ^ 1) * 8192 + (j * 512 + w * 64) * 8);
                GLOAD_LDS16(Vt + vtbase + (kp0 + 64) + vofs[j],
                            VldsBase + (cur ^ 1) * 8192 + (j * 512 + w * 64) * 8);
            }
        }
        const char* Kb = smem + cur * 16384;
        const char* Vb = smem + 32768 + cur * 16384;

        const bool lo_act = (kt <= ilo);
        // ---- S^T = K Q^T over this wave's kv half: A = K fragment, B = Q fragment ----
        f32x4 sl[2] = {}, sh[2] = {};
        __builtin_amdgcn_s_setprio(1);
        #pragma unroll
        for (int ct = 0; ct < 2; ++ct) {
            #pragma unroll
            for (int d = 0; d < 4; ++d) {
                int row = half * 32 + ct * 16 + lr;
                int bo = row * 256 + ((d * 64 + lq * 16) ^ ((row & 7) << 4));
                bf16x8 kf = *reinterpret_cast<const bf16x8*>(Kb + bo);
                sh[ct] = __builtin_amdgcn_mfma_f32_16x16x32_bf16(kf, qfh[d], sh[ct], 0, 0, 0);
                if (lo_act) sl[ct] = __builtin_amdgcn_mfma_f32_16x16x32_bf16(kf, qfl[d], sl[ct], 0, 0, 0);
            }
        }
        __builtin_amdgcn_s_setprio(0);

        // ---- fixed-shift softmax fully in-register: P fragment = 4x cvt_pk ----
        const int kvb = kp0 + half * 32 + lq * 4;    // kv of (ct=0, r=0)
        bf16x8 pfh, pfl;
        {
            const bool diag = (kt == nkt - 1);
            float e[2][4];
            #pragma unroll
            for (int ct = 0; ct < 2; ++ct)
                #pragma unroll
                for (int r = 0; r < 4; ++r)
                    e[ct][r] = exp2f(sh[ct][r]);
            if (diag) {
                #pragma unroll
                for (int ct = 0; ct < 2; ++ct)
                    #pragma unroll
                    for (int r = 0; r < 4; ++r)
                        if (kvb + ct * 16 + r > qhi) e[ct][r] = 0.f;
            }
            u32x4 pk;
            pk[0] = cvt_pk_bf16(e[0][0], e[0][1]);
            pk[1] = cvt_pk_bf16(e[0][2], e[0][3]);
            pk[2] = cvt_pk_bf16(e[1][0], e[1][1]);
            pk[3] = cvt_pk_bf16(e[1][2], e[1][3]);
            pfh = __builtin_bit_cast(bf16x8, pk);
        }
        if (lo_act) {
            const bool diag = (kt == ilo);
            float e[2][4];
            #pragma unroll
            for (int ct = 0; ct < 2; ++ct)
                #pragma unroll
                for (int r = 0; r < 4; ++r)
                    e[ct][r] = exp2f(sl[ct][r]);
            if (diag) {
                #pragma unroll
                for (int ct = 0; ct < 2; ++ct)
                    #pragma unroll
                    for (int r = 0; r < 4; ++r)
                        if (kvb + ct * 16 + r > qlo) e[ct][r] = 0.f;
            }
            u32x4 pk;
            pk[0] = cvt_pk_bf16(e[0][0], e[0][1]);
            pk[1] = cvt_pk_bf16(e[0][2], e[0][3]);
            pk[2] = cvt_pk_bf16(e[1][0], e[1][1]);
            pk[3] = cvt_pk_bf16(e[1][2], e[1][3]);
            pfl = __builtin_bit_cast(bf16x8, pk);
        }

        // ---- O^T += V^T P ; l += ones . P  (A = V fragment, B = P fragment) ----
        __builtin_amdgcn_s_setprio(1);
        #pragma unroll
        for (int n = 0; n < 8; ++n) {
            int vrow = n * 16 + lr;
            int bv = vrow * 128 + ((half * 64 + lq * 16) ^ ((vrow & 7) << 4));
            bf16x8 vf = *reinterpret_cast<const bf16x8*>(Vb + bv);
            oh[n] = __builtin_amdgcn_mfma_f32_16x16x32_bf16(vf, pfh, oh[n], 0, 0, 0);
            if (lo_act) ol[n] = __builtin_amdgcn_mfma_f32_16x16x32_bf16(vf, pfl, ol[n], 0, 0, 0);
        }
        lsh = __builtin_amdgcn_mfma_f32_16x16x32_bf16(ones, pfh, lsh, 0, 0, 0);
        if (lo_act) lsl = __builtin_amdgcn_mfma_f32_16x16x32_bf16(ones, pfl, lsl, 0, 0, 0);
        __builtin_amdgcn_s_setprio(0);
        cur ^= 1;
    }

    // ---- epilogue: combine kv halves via LDS (alias dead K/V bufs), normalize, store ----
    // lane holds O[q = group+lr][d = n*16+lq*4+r]; l[q] replicated in lsh/lsl lanes.
    __syncthreads();
    float* Osh = (float*)smem;                   // [128 rows][132] f32 (pad -> 2-way banks)
    float* Lsh = (float*)(smem + 128 * 132 * 4); // [128] f32
    if (half == 1) {
        #pragma unroll
        for (int n = 0; n < 8; ++n) {
            *reinterpret_cast<f32x4*>(&Osh[(wq * 32 + lr) * 132 + n * 16 + lq * 4]) = oh[n];
            *reinterpret_cast<f32x4*>(&Osh[(wq * 32 + 16 + lr) * 132 + n * 16 + lq * 4]) = ol[n];
        }
        if (lq == 0) {
            Lsh[wq * 32 + lr] = lsh[0];
            Lsh[wq * 32 + 16 + lr] = lsl[0];
        }
    }
    __syncthreads();
    if (half == 0) {
        const float invh = 1.f / (lsh[0] + Lsh[wq * 32 + lr]);
        const float invl = 1.f / (lsl[0] + Lsh[wq * 32 + 16 + lr]);
        u16* outh = Out + ((size_t)(b * Tt) + ihi * 64 + wq * 16 + lr) * EMB + h * HD;
        u16* outl = Out + ((size_t)(b * Tt) + ilo * 64 + wq * 16 + lr) * EMB + h * HD;
        #pragma unroll
        for (int n = 0; n < 8; ++n) {
            f32x4 sh4 = *reinterpret_cast<const f32x4*>(&Osh[(wq * 32 + lr) * 132 + n * 16 + lq * 4]);
            f32x4 sl4 = *reinterpret_cast<const f32x4*>(&Osh[(wq * 32 + 16 + lr) * 132 + n * 16 + lq * 4]);
            uint2 ph, pl;
            ph.x = cvt_pk_bf16((oh[n][0] + sh4[0]) * invh, (oh[n][1] + sh4[1]) * invh);
            ph.y = cvt_pk_bf16((oh[n][2] + sh4[2]) * invh, (oh[n][3] + sh4[3]) * invh);
            pl.x = cvt_pk_bf16((ol[n][0] + sl4[0]) * invl, (ol[n][1] + sl4[1]) * invl);
            pl.y = cvt_pk_bf16((ol[n][2] + sl4[2]) * invl, (ol[n][3] + sl4[3]) * invl);
            *reinterpret_cast<uint2*>(&outh[n * 16 + lq * 4]) = ph;
            *reinterpret_cast<uint2*>(&outl[n * 16 + lq * 4]) = pl;
        }
    }
}

// ---------------- launcher ----------------
extern "C" void kernel_launch(void* const* d_in, const int* in_sizes, int n_in,
                              void* d_out, int out_size, void* d_ws, size_t ws_size,
                              hipStream_t stream) {
    (void)in_sizes; (void)n_in; (void)out_size; (void)ws_size;
    const float* x  = (const float*)d_in[0];
    const float* Wq = (const float*)d_in[1];
    const float* Wk = (const float*)d_in[2];
    const float* Wv = (const float*)d_in[3];
    const float* Wo = (const float*)d_in[4];
    float* out = (float*)d_out;

    char* ws = (char*)d_ws;
    size_t off = 0;
    auto alloc = [&](size_t bytes) { char* p = ws + off; off += (bytes + 255) & ~(size_t)255; return p; };

    u16* w_bf    = (u16*)alloc((size_t)(QKVN * EMB + EMB * EMB) * 2);  // Wq|Wk|Wv then Wo
    u16* x_bf    = (u16*)alloc((size_t)MROWS * EMB * 2);
    u16* qkv_lin = (u16*)alloc((size_t)MROWS * QKVN * 4);              // bf16 used; f32-size kept
    u16* Qb      = (u16*)alloc((size_t)Bb * NHq * Tt * HD * 2);
    u16* Kb      = (u16*)alloc((size_t)Bb * NGk * Tt * HD * 2);
    u16* Vtb     = (u16*)alloc((size_t)Bb * NGk * HD * Tt * 2);
    float* ctab  = (float*)alloc((size_t)Tt * 64 * 4);
    float* stab  = (float*)alloc((size_t)Tt * 64 * 4);
    u16* attnout = qkv_lin;         // alias: qkv_lin dead after rope/vtrans

    u16* wo_bf = w_bf + (size_t)QKVN * EMB;

    // 1. casts (x + fused weights) + tables
    cast_bf16_kernel<<<(MROWS * EMB / 4 + 255) / 256, 256, 0, stream>>>(x, x_bf, MROWS * EMB / 4);
    wcast_kernel<<<(QKVN * EMB + EMB * EMB) / 4 / 256, 256, 0, stream>>>(Wq, Wk, Wv, Wo, w_bf);
    rope_tables_kernel<<<Tt, 64, 0, stream>>>(ctab, stab);

    // 2. fused QKV projection: qkv_lin[4096][3072] bf16 = x_bf @ [Wq;Wk;Wv]^T
    gemm_bt<1><<<dim3(MROWS / 128, QKVN / 128), 256, 0, stream>>>(x_bf, w_bf, qkv_lin, MROWS, QKVN, EMB);

    // 3. RoPE q+k (fused) + V transpose (+ fold softmax scale*log2e into Q)
    const float qscale = 1.44269504088896f / sqrtf((float)HD);
    rope_qk_kernel<<<dim3(Tt / 4, NHq + NGk, Bb), dim3(64, 4), 0, stream>>>(qkv_lin, ctab, stab, Qb, Kb, qscale);
    vtrans_kernel<<<dim3(Tt / 64, NGk, Bb), dim3(64, 8), 0, stream>>>(qkv_lin, Vtb);

    // 4. flash attention (swapped QK^T, in-register P) -> attnout bf16 [B][T][EMB]
    flash_attn<<<dim3(NQT / 2, NHq, Bb), 512, 0, stream>>>(Qb, Kb, Vtb, attnout);

    // 5. output projection: out = attnout @ Wo^T  (f32 out)
    gemm_bt<0><<<dim3(MROWS / 128, EMB / 128), 256, 0, stream>>>(attnout, wo_bf, out, MROWS, EMB, EMB);
}